// Round 1
// 530.226 us; speedup vs baseline: 1.0087x; 1.0087x over previous
//
#include <hip/hip_runtime.h>
#include <math.h>

// AxileAttention: out = softmax((X@Wq+bq)*(X@Wk+bk), -1) * (X@Wv+bv), per (b,c).
// B=8 C=64 H=256 W=256, fp32 in/out.
//
// Round 8: occupancy fix. R7 was reg-occupancy-bound: 128 arch VGPR + 128 live
// acc floats (accq+acck) = ~256 regs/wave -> 8 waves/CU (23% occ), latency-bound
// (MfmaUtil 13%, HBM 15%). Restructure to 512-thread blocks (8 waves), each wave
// owns a 64x32 column strip -> acc halves to 64 f32/thread -> target <=128
// regs/wave -> 16 waves/CU. Same grid, same LDS fragment layout, same HBM
// traffic; per-thread staging work also halves.
// Two-phase K-loop as before:
//   phase 1: q,k (split-f16, 3-MFMA each) -> s=q*k -> softmax e (32 regs)
//   phase 2: v (single f16) second K-pass, accv 32 regs; out = e*(v+bv)*inv.
// Wave tile 64x32, mfma_f32_32x32x16_f16. Waves = 8 ncol strips.

#define Bn 8
#define Cn 64
#define Hn 256
#define Wn 256

typedef _Float16 f16x8 __attribute__((ext_vector_type(8)));
typedef _Float16 f16x4 __attribute__((ext_vector_type(4)));
typedef float    f32x16 __attribute__((ext_vector_type(16)));

#define MFMA(a, b, c) __builtin_amdgcn_mfma_f32_32x32x16_f16((a), (b), (c), 0, 0, 0)

// LDS layout (39.4 KB -> 2 blocks/CU = 16 waves/CU):
//   A hi: [0,2048)       mtile*1024 + slot*16
//   A lo: [2048,4096)
//   B:    [4096,36864)   plane p*8192 + ntile*1024 + slot*16
//         phase1 planes: 0=qh 1=ql 2=kh 3=kl; phase2: plane 0 = vh
//   smx:  [36864,39424)  part[8][64] @0, combmax[64] @2048, combsum[64] @2304
#define LDS_ALO 2048
#define LDS_B   4096
#define LDS_SM  36864

__global__ __launch_bounds__(512, 4) void axile_attn_mfma4(
    const float* __restrict__ x,
    const float* __restrict__ wq,
    const float* __restrict__ wk,
    const float* __restrict__ wv,
    const float* __restrict__ bq,
    const float* __restrict__ bk,
    const float* __restrict__ bv,
    float* __restrict__ out)
{
    __shared__ __align__(16) char lds[39424];

    const int tid  = threadIdx.x;
    const int ncol = tid >> 6;     // wave id = column strip 0..7
    const int lane = tid & 63;
    const int h    = lane >> 5;
    const int l31  = lane & 31;

    // blk = j*64 + c  (c in low bits -> blk%8==c%8: XCD affinity per channel)
    const int blk = blockIdx.x;
    const int c   = blk & 63;
    const int j   = blk >> 6;      // 0..31 = b*4 + ht
    const int b   = j >> 2;
    const int h0  = (j & 3) * 64;

    const float* xbase = x + ((size_t)(b * Cn + c) * Hn + h0) * Wn;
    const float* w_q = wq + (size_t)c * Wn * Wn;
    const float* w_k = wk + (size_t)c * Wn * Wn;
    const float* w_v = wv + (size_t)c * Wn * Wn;

    // W staging: thread = (khalf = tid>>8, column n = tid&255); loads 8 k-rows.
    const int wkh = tid >> 8;            // which 8-row half of the 16-k tile
    const int n   = tid & 255;           // column
    const int ntW = n >> 5;
    const int nl  = n & 31;
    const int wfo = ((wkh << 5) | nl) * 16;   // fragment slot byte offset
    // X staging (tid<256): thread = (row m = tid>>2, kq = tid&3) -> float4.
    const int am    = tid >> 2;          // 0..63
    const int akq   = tid & 3;
    const int amt   = am >> 5;
    const int alc   = ((akq >> 1) << 5) | (am & 31);
    const int aboff = (akq & 1) * 8;

    f32x16 accq[2], acck[2];
#pragma unroll
    for (int mt = 0; mt < 2; ++mt)
#pragma unroll
        for (int r = 0; r < 16; ++r) {
            accq[mt][r] = 0.f;
            acck[mt][r] = 0.f;
        }

    // ================= phase 1: q,k =================
    for (int kt = 0; kt < 16; ++kt) {
        const int k0 = kt * 16;
        __syncthreads();
        // stage Wq, Wk (hi+lo): 8 k-rows per thread-column, coalesced per row
#pragma unroll
        for (int mat = 0; mat < 2; ++mat) {
            const float* Wp = mat ? w_k : w_q;
            const float* wrow = Wp + (size_t)(k0 + wkh * 8) * Wn + n;
            float w8[8];
#pragma unroll
            for (int r = 0; r < 8; ++r)
                w8[r] = wrow[(size_t)r * Wn];
            f16x8 hi8, lo8;
#pragma unroll
            for (int e = 0; e < 8; ++e) {
                const float wv_ = w8[e];
                _Float16 hv = (_Float16)wv_;
                hi8[e] = hv;
                lo8[e] = (_Float16)(wv_ - (float)hv);
            }
            char* dplane = lds + LDS_B + (mat * 2) * 8192 + ntW * 1024;
            *(f16x8*)(dplane + wfo) = hi8;
            *(f16x8*)(dplane + 8192 + wfo) = lo8;
        }
        // stage X (hi+lo) — first 4 waves only
        if (tid < 256) {
            const float4 xx = *(const float4*)(xbase + (size_t)am * Wn + k0 + akq * 4);
            f16x4 hi4, lo4;
            _Float16 t0 = (_Float16)xx.x; hi4[0] = t0; lo4[0] = (_Float16)(xx.x - (float)t0);
            _Float16 t1 = (_Float16)xx.y; hi4[1] = t1; lo4[1] = (_Float16)(xx.y - (float)t1);
            _Float16 t2 = (_Float16)xx.z; hi4[2] = t2; lo4[2] = (_Float16)(xx.z - (float)t2);
            _Float16 t3 = (_Float16)xx.w; hi4[3] = t3; lo4[3] = (_Float16)(xx.w - (float)t3);
            *(f16x4*)(lds + amt * 1024 + alc * 16 + aboff) = hi4;
            *(f16x4*)(lds + LDS_ALO + amt * 1024 + alc * 16 + aboff) = lo4;
        }
        __syncthreads();

        f16x8 ah[2], al[2];
#pragma unroll
        for (int mt = 0; mt < 2; ++mt) {
            ah[mt] = *(const f16x8*)(lds + mt * 1024 + lane * 16);
            al[mt] = *(const f16x8*)(lds + LDS_ALO + mt * 1024 + lane * 16);
        }
        const char* bb = lds + LDS_B + ncol * 1024 + lane * 16;
        f16x8 bqh = *(const f16x8*)(bb + 0 * 8192);
        f16x8 bql = *(const f16x8*)(bb + 1 * 8192);
        f16x8 bkh = *(const f16x8*)(bb + 2 * 8192);
        f16x8 bkl = *(const f16x8*)(bb + 3 * 8192);
#pragma unroll
        for (int mt = 0; mt < 2; ++mt) {
            accq[mt] = MFMA(ah[mt], bqh, accq[mt]);
            accq[mt] = MFMA(al[mt], bqh, accq[mt]);
            accq[mt] = MFMA(ah[mt], bql, accq[mt]);
            acck[mt] = MFMA(ah[mt], bkh, acck[mt]);
            acck[mt] = MFMA(al[mt], bkh, acck[mt]);
            acck[mt] = MFMA(ah[mt], bkl, acck[mt]);
        }
    }

    float* part    = (float*)(lds + LDS_SM);          // [8][64]  (wave-major: conflict-free combine)
    float* combmax = (float*)(lds + LDS_SM + 2048);   // [64]
    float* combsum = (float*)(lds + LDS_SM + 2304);   // [64]

    // ---- bias add; s = q*k into accq (acck dies here) ----
#pragma unroll
    for (int mt = 0; mt < 2; ++mt)
#pragma unroll
        for (int r = 0; r < 16; ++r) {
            const int rl = (r & 3) + 8 * (r >> 2) + 4 * h;
            const int hh = h0 + mt * 32 + rl;
            const int vv = ncol * 32 + l31;
            const size_t bidx = ((size_t)c * Hn + hh) * Wn + vv;
            const float qv = accq[mt][r] + bq[bidx];
            const float kv = acck[mt][r] + bk[bidx];
            accq[mt][r] = qv * kv;
        }

    // ---- row max (reduce over 32-lane half; h stays separate) ----
#pragma unroll
    for (int mt = 0; mt < 2; ++mt)
#pragma unroll
        for (int r = 0; r < 16; ++r) {
            float m2 = accq[mt][r];
#pragma unroll
            for (int off = 16; off > 0; off >>= 1)
                m2 = fmaxf(m2, __shfl_xor(m2, off, 64));
            if ((lane & 15) == r && ((lane >> 4) & 1) == mt) {
                const int rl  = (r & 3) + 8 * (r >> 2) + 4 * h;
                const int row = mt * 32 + rl;
                part[ncol * 64 + row] = m2;
            }
        }
    __syncthreads();
    if (tid < 64) {
        float m = part[tid];
#pragma unroll
        for (int w = 1; w < 8; ++w)
            m = fmaxf(m, part[w * 64 + tid]);
        combmax[tid] = m;
    }
    __syncthreads();

    // ---- e = exp(s - mx) into accq; row sum ----
#pragma unroll
    for (int mt = 0; mt < 2; ++mt)
#pragma unroll
        for (int r = 0; r < 16; ++r) {
            const int rl  = (r & 3) + 8 * (r >> 2) + 4 * h;
            const int row = mt * 32 + rl;
            const float mx = combmax[row];
            const float e0 = __expf(accq[mt][r] - mx);
            accq[mt][r] = e0;
            float ps = e0;
#pragma unroll
            for (int off = 16; off > 0; off >>= 1)
                ps += __shfl_xor(ps, off, 64);
            if ((lane & 15) == r && ((lane >> 4) & 1) == mt)
                part[ncol * 64 + row] = ps;
        }
    __syncthreads();
    if (tid < 64) {
        float s = part[tid];
#pragma unroll
        for (int w = 1; w < 8; ++w)
            s += part[w * 64 + tid];
        combsum[tid] = s;
    }
    // (phase-2 first barrier covers combsum visibility)

    // ================= phase 2: v =================
    f32x16 accv[2];
#pragma unroll
    for (int mt = 0; mt < 2; ++mt)
#pragma unroll
        for (int r = 0; r < 16; ++r)
            accv[mt][r] = 0.f;

    for (int kt = 0; kt < 16; ++kt) {
        const int k0 = kt * 16;
        __syncthreads();
        // stage Wv (hi only) into B plane 0
        {
            const float* wrow = w_v + (size_t)(k0 + wkh * 8) * Wn + n;
            float w8[8];
#pragma unroll
            for (int r = 0; r < 8; ++r)
                w8[r] = wrow[(size_t)r * Wn];
            f16x8 hi8;
#pragma unroll
            for (int e = 0; e < 8; ++e)
                hi8[e] = (_Float16)w8[e];
            *(f16x8*)(lds + LDS_B + ntW * 1024 + wfo) = hi8;
        }
        // stage X (hi only) — first 4 waves only
        if (tid < 256) {
            const float4 xx = *(const float4*)(xbase + (size_t)am * Wn + k0 + akq * 4);
            f16x4 hi4;
            hi4[0] = (_Float16)xx.x;
            hi4[1] = (_Float16)xx.y;
            hi4[2] = (_Float16)xx.z;
            hi4[3] = (_Float16)xx.w;
            *(f16x4*)(lds + amt * 1024 + alc * 16 + aboff) = hi4;
        }
        __syncthreads();

        f16x8 ah[2];
#pragma unroll
        for (int mt = 0; mt < 2; ++mt)
            ah[mt] = *(const f16x8*)(lds + mt * 1024 + lane * 16);
        f16x8 bvh = *(const f16x8*)(lds + LDS_B + ncol * 1024 + lane * 16);
#pragma unroll
        for (int mt = 0; mt < 2; ++mt)
            accv[mt] = MFMA(ah[mt], bvh, accv[mt]);
    }

    // ---- out = e * (v + bv) / sum ----
    float* obase = out + ((size_t)(b * Cn + c) * Hn) * Wn;
#pragma unroll
    for (int mt = 0; mt < 2; ++mt)
#pragma unroll
        for (int r = 0; r < 16; ++r) {
            const int rl  = (r & 3) + 8 * (r >> 2) + 4 * h;
            const int row = mt * 32 + rl;
            const float inv = 1.0f / combsum[row];
            const int hh = h0 + row;
            const int vv = ncol * 32 + l31;
            const size_t bidx = ((size_t)c * Hn + hh) * Wn + vv;
            const float vx = accv[mt][r] + bv[bidx];
            obase[(size_t)hh * Wn + vv] = accq[mt][r] * vx * inv;
        }
}

extern "C" void kernel_launch(void* const* d_in, const int* in_sizes, int n_in,
                              void* d_out, int out_size, void* d_ws, size_t ws_size,
                              hipStream_t stream) {
    (void)in_sizes; (void)n_in; (void)out_size; (void)d_ws; (void)ws_size;
    const float* x  = (const float*)d_in[0];
    const float* wq = (const float*)d_in[1];
    const float* wk = (const float*)d_in[2];
    const float* wv = (const float*)d_in[3];
    const float* bq = (const float*)d_in[4];
    const float* bk = (const float*)d_in[5];
    const float* bv = (const float*)d_in[6];
    float* out = (float*)d_out;

    dim3 grid(Bn * 4 * Cn);   // 2048 blocks: blk = (b*4+ht)*64 + c
    dim3 block(512);          // 8 waves, one 64x32 strip each
    hipLaunchKernelGGL(axile_attn_mfma4, grid, block, 0, stream,
                       x, wq, wk, wv, bq, bk, bv, out);
}